// Round 5
// baseline (484.808 us; speedup 1.0000x reference)
//
#include <hip/hip_runtime.h>

// Problem constants (from reference: shape (2,1,384,1248), MAXDISP=128, C=1)
#define NB 2
#define HH 384
#define WW 1248
#define W4 (WW / 4)        // 312 float4 per row
#define MAXDISP 128
#define DPT 8              // disparities per thread (must be multiple of 4)

// Clang-native 4-float vector: required by __builtin_nontemporal_store
// (HIP's float4 is a class type the builtin rejects).
using f32x4 = __attribute__((ext_vector_type(4))) float;

// out[n, d, y, x] = x >= d ? |img1[n,0,y,x] - img2[n,0,y,x-d]| : 0
// Output layout: ((n*128 + d)*384 + y)*1248 + x   (C==1)
//
// Traffic-bound kernel. v3: DPT=8 d-blocking — each thread produces the
// same (y, x..x+3) strip for 8 consecutive disparities d0..d0+7, reusing
// one img1 vector and THREE aligned img2 vectors (register shift window).
// Loads per output vector: 0.5 (was 0.75 at DPT=4, 2.0 at DPT=1).
//
// Alignment fact: x = 4*x4 and d0 = 8*blockIdx.y are multiples of 4, so
// s = x - d0 is a multiple of 4. The img2 window needed for dd=0..7 is
// elements [s-7, s+3], covered by aligned vectors at s-8, s-4, s.
// Clamped load addresses keep OOB lanes in-bounds; per-element masks
// (s - dd + j >= 0) zero them, compiling to cndmask (no divergence).
__global__ __launch_bounds__(256) void cost_volume_kernel(
    const float* __restrict__ img1,
    const float* __restrict__ img2,
    float* __restrict__ out)
{
    const int d0 = blockIdx.y * DPT;    // disparity group base: 0,8,...,120
    const int n  = blockIdx.z;          // batch 0..1

    // flat index over (y, x4) for this (n, d-group) slice
    const int idx = blockIdx.x * 256 + threadIdx.x;   // 0 .. H*W4-1 (468*256 exact)
    const int x4  = idx % W4;
    const int y   = idx / W4;
    const int x   = x4 * 4;

    const float* __restrict__ row1 = img1 + (n * HH + y) * WW;
    const float* __restrict__ row2 = img2 + (n * HH + y) * WW;

    // output vector pointers: ((n*D + d0+dd)*H*W4) + idx, stride H*W4 per dd
    const size_t dstride = (size_t)HH * W4;
    f32x4* o0 = (f32x4*)out + (size_t)(n * MAXDISP + d0) * dstride + (size_t)idx;

    const int s = x - d0;               // shifted source col, multiple of 4

    if (s < 0) {
        // s <= -4: every output element has source index <= s+3 <= -1 -> all zero
        const f32x4 z = {0.f, 0.f, 0.f, 0.f};
        #pragma unroll
        for (int dd = 0; dd < DPT; ++dd)
            __builtin_nontemporal_store(z, o0 + dd * dstride);
        return;
    }

    const f32x4 a = *(const f32x4*)(row1 + x);         // img1[x..x+3]

    // img2 window w[i] = row2[s - DPT + i], i = 0 .. DPT+3
    // (vectors below s are clamped to row2[0]; masked out later)
    float w[DPT + 4];
    #pragma unroll
    for (int k = 0; k < DPT / 4 + 1; ++k) {
        const int base = s - DPT + 4 * k;
        const f32x4 v = *(const f32x4*)(row2 + max(base, 0));
        w[4 * k + 0] = v.x;
        w[4 * k + 1] = v.y;
        w[4 * k + 2] = v.z;
        w[4 * k + 3] = v.w;
    }

    // dd-th output, j-th element sources img2[s - dd + j] = w[DPT - dd + j]
    #pragma unroll
    for (int dd = 0; dd < DPT; ++dd) {
        f32x4 o;
        #pragma unroll
        for (int j = 0; j < 4; ++j) {
            const float v = fabsf(a[j] - w[DPT - dd + j]);
            o[j] = (s - dd + j >= 0) ? v : 0.f;
        }
        __builtin_nontemporal_store(o, o0 + dd * dstride);
    }
}

extern "C" void kernel_launch(void* const* d_in, const int* in_sizes, int n_in,
                              void* d_out, int out_size, void* d_ws, size_t ws_size,
                              hipStream_t stream) {
    const float* img1 = (const float*)d_in[0];
    const float* img2 = (const float*)d_in[1];
    float* out = (float*)d_out;

    // H*W4 = 384*312 = 119808 = 468 * 256 exactly
    dim3 grid((HH * W4) / 256, MAXDISP / DPT, NB);
    dim3 block(256);
    cost_volume_kernel<<<grid, block, 0, stream>>>(img1, img2, out);
}